// Round 12
// baseline (124.190 us; speedup 1.0000x reference)
//
#include <hip/hip_runtime.h>

// ---------------------------------------------------------------------------
// Pipeline (algebraically restructured from the reference):
//   Xb = bf16(node_features), Hb = bf16(hedge_features)
//   A[n,:]  = sum_{e: rcv=n} conv_e * Xb[snd_e,:]           (f32 acc -> bf16)
//   c1[n]   = sum_{e: rcv=n} conv_e
//   B[n,:]  = sum_{e2} conv2_e * Hb[snd_e,:]                (f32 acc -> bf16)
//   c2[n]   = sum conv2_e
//   out     = (A@Wm + c1*bm) .* (B@Ws + c2*bs)   -- bf16 MFMA, f32 accum
//
// R12: prep split for overlap. prep_node (cvt X + ro1) gates scatter_node;
// prep_rest (cvt H + ro2 + W transposes) is dispatched AFTER scatter_node so
// its blocks fill scatter_node's drain tail (in-order queue overlap).
// Scatters/gemm identical to R11 (best measured; scatter_node is at the
// ~3.25 TB/s random-row fabric floor — pinning variants R6-R8 all lost).
// ---------------------------------------------------------------------------

typedef __attribute__((ext_vector_type(8))) short bf16x8;
typedef __attribute__((ext_vector_type(4))) float f32x4;
typedef __attribute__((ext_vector_type(4))) unsigned short u16x4;
typedef __attribute__((ext_vector_type(2))) unsigned short u16x2;

static __device__ __forceinline__ unsigned short f2bf(float f) {
  unsigned u = __float_as_uint(f);
  u += 0x7fff + ((u >> 16) & 1);          // round-to-nearest-even
  return (unsigned short)(u >> 16);
}
static __device__ __forceinline__ float bf2f(unsigned short h) {
  return __uint_as_float((unsigned)h << 16);
}

// ---------------------------------------------------------------------------
// prep_node: [0,bX) cvt X f32->bf16 ; [bX,bX+bE1) row offsets for rcv1.
// Gates scatter_node only.
// ---------------------------------------------------------------------------
__global__ __launch_bounds__(256) void prep_node(
    const float* __restrict__ X,
    const int* __restrict__ rcv1, int E1, int N,
    unsigned short* __restrict__ Xb,
    int* __restrict__ ro1,
    int nX4)
{
  const int tid = (int)threadIdx.x;
  int b = (int)blockIdx.x;
  const int bX = (nX4 + 255) / 256;

  if (b < bX) {                       // ---- cvt X ----
    const int i = b * 256 + tid;
    if (i < nX4) {
      const float4 v = reinterpret_cast<const float4*>(X)[i];
      reinterpret_cast<ushort4*>(Xb)[i] =
          make_ushort4(f2bf(v.x), f2bf(v.y), f2bf(v.z), f2bf(v.w));
    }
    return;
  }
  b -= bX;
  {                                   // ---- row offsets 1 ----
    const int e = b * 256 + tid;
    if (e < E1) {
      const int c = rcv1[e];
      const int p = (e == 0) ? -1 : rcv1[e - 1];
      for (int n = p + 1; n <= c; ++n) ro1[n] = e;
      if (e == E1 - 1)
        for (int n = c + 1; n <= N; ++n) ro1[n] = E1;
    }
  }
}

// ---------------------------------------------------------------------------
// prep_rest: [0,bH) cvt H ; [bH,+bE2) ro2 ; [..,+64) transpose Wm ;
// [..,+32) transpose Ws. Gates scatter_hedge / gemm only — dispatched after
// scatter_node to overlap with its drain tail.
// ---------------------------------------------------------------------------
__global__ __launch_bounds__(256) void prep_rest(
    const float* __restrict__ H,
    const int* __restrict__ rcv2, int E2, int N,
    const float* __restrict__ Wm, const float* __restrict__ Ws,
    unsigned short* __restrict__ Hb,
    int* __restrict__ ro2,
    unsigned short* __restrict__ WmT, unsigned short* __restrict__ WsT,
    int nH4)
{
  __shared__ float t[32][33];
  const int tid = (int)threadIdx.x;
  int b = (int)blockIdx.x;
  const int bH  = (nH4 + 255) / 256;
  const int bE2 = (E2 + 255) / 256;

  if (b < bH) {                       // ---- cvt H ----
    const int i = b * 256 + tid;
    if (i < nH4) {
      const float4 v = reinterpret_cast<const float4*>(H)[i];
      reinterpret_cast<ushort4*>(Hb)[i] =
          make_ushort4(f2bf(v.x), f2bf(v.y), f2bf(v.z), f2bf(v.w));
    }
    return;
  }
  b -= bH;
  if (b < bE2) {                      // ---- row offsets 2 ----
    const int e = b * 256 + tid;
    if (e < E2) {
      const int c = rcv2[e];
      const int p = (e == 0) ? -1 : rcv2[e - 1];
      for (int n = p + 1; n <= c; ++n) ro2[n] = e;
      if (e == E2 - 1)
        for (int n = c + 1; n <= N; ++n) ro2[n] = E2;
    }
    return;
  }
  b -= bE2;
  {
    // ---- weight transposes: Wm tiles [0,64), Ws tiles [64,96) ----
    const float* W; unsigned short* WT; int K, Nn, tile;
    if (b < 64) { W = Wm; WT = WmT; K = 256; Nn = 256; tile = b; }
    else        { W = Ws; WT = WsT; K = 128; Nn = 256; tile = b - 64; }
    const int ntiles_n = Nn / 32;
    const int n0 = (tile % ntiles_n) * 32;
    const int k0 = (tile / ntiles_n) * 32;
    const int tx = tid & 31, ty = tid >> 5;   // 32 x 8
#pragma unroll
    for (int i = 0; i < 32; i += 8)
      t[ty + i][tx] = W[(size_t)(k0 + ty + i) * Nn + n0 + tx];
    __syncthreads();
#pragma unroll
    for (int i = 0; i < 32; i += 8)
      WT[(size_t)(n0 + ty + i) * K + k0 + tx] = f2bf(t[tx][ty + i]);
  }
}

// One wave per node, C=256 bf16 channels (ushort4 per lane). No atomics.
// 16/4/1 unmasked batches (fastest measured); nt idx loads, nt A/c store.
__global__ __launch_bounds__(256) void scatter_node_seg(
    const unsigned short* __restrict__ X,   // [Nsrc,256] bf16
    const int* __restrict__ snd,
    const float* __restrict__ conv,
    const int* __restrict__ row_start,      // [N+1]
    unsigned short* __restrict__ A,         // [Mp,256] bf16
    float* __restrict__ csum,               // [Mp]
    int N)
{
  const int lane = threadIdx.x & 63;
  const int node = __builtin_amdgcn_readfirstlane(
      (int)blockIdx.x * 4 + ((int)threadIdx.x >> 6));
  if (node >= N) return;
  const int lo = row_start[node];
  const int hi = row_start[node + 1];

  const unsigned short* Xl = X + lane * 4;
  float4 acc = make_float4(0.f, 0.f, 0.f, 0.f);
  float cacc = 0.f;

  int e = lo;
  for (; e + 16 <= hi; e += 16) {
    int s[16]; float cv[16]; ushort4 x[16];
#pragma unroll
    for (int j = 0; j < 16; ++j) s[j] = __builtin_nontemporal_load(snd + e + j);
#pragma unroll
    for (int j = 0; j < 16; ++j) cv[j] = __builtin_nontemporal_load(conv + e + j);
#pragma unroll
    for (int j = 0; j < 16; ++j)
      x[j] = *reinterpret_cast<const ushort4*>(Xl + (size_t)s[j] * 256);
#pragma unroll
    for (int j = 0; j < 16; ++j) {
      acc.x = fmaf(cv[j], bf2f(x[j].x), acc.x);
      acc.y = fmaf(cv[j], bf2f(x[j].y), acc.y);
      acc.z = fmaf(cv[j], bf2f(x[j].z), acc.z);
      acc.w = fmaf(cv[j], bf2f(x[j].w), acc.w);
      cacc += cv[j];
    }
  }
  for (; e + 4 <= hi; e += 4) {
    int s[4]; float cv[4]; ushort4 x[4];
#pragma unroll
    for (int j = 0; j < 4; ++j) s[j] = __builtin_nontemporal_load(snd + e + j);
#pragma unroll
    for (int j = 0; j < 4; ++j) cv[j] = __builtin_nontemporal_load(conv + e + j);
#pragma unroll
    for (int j = 0; j < 4; ++j)
      x[j] = *reinterpret_cast<const ushort4*>(Xl + (size_t)s[j] * 256);
#pragma unroll
    for (int j = 0; j < 4; ++j) {
      acc.x = fmaf(cv[j], bf2f(x[j].x), acc.x);
      acc.y = fmaf(cv[j], bf2f(x[j].y), acc.y);
      acc.z = fmaf(cv[j], bf2f(x[j].z), acc.z);
      acc.w = fmaf(cv[j], bf2f(x[j].w), acc.w);
      cacc += cv[j];
    }
  }
  for (; e < hi; ++e) {
    const int s = snd[e];
    const float cv = conv[e];
    const ushort4 x = *reinterpret_cast<const ushort4*>(Xl + (size_t)s * 256);
    acc.x = fmaf(cv, bf2f(x.x), acc.x);
    acc.y = fmaf(cv, bf2f(x.y), acc.y);
    acc.z = fmaf(cv, bf2f(x.z), acc.z);
    acc.w = fmaf(cv, bf2f(x.w), acc.w);
    cacc += cv;
  }

  u16x4 r;
  r[0] = f2bf(acc.x); r[1] = f2bf(acc.y);
  r[2] = f2bf(acc.z); r[3] = f2bf(acc.w);
  __builtin_nontemporal_store(
      r, reinterpret_cast<u16x4*>(A + (size_t)node * 256 + lane * 4));
  if (lane == 0) __builtin_nontemporal_store(cacc, csum + node);
}

// One wave per node, C=128 bf16 channels (ushort2 per lane). No atomics.
__global__ __launch_bounds__(256) void scatter_hedge_seg(
    const unsigned short* __restrict__ X,   // [Nsrc,128] bf16
    const int* __restrict__ snd,
    const float* __restrict__ conv,
    const int* __restrict__ row_start,      // [N+1]
    unsigned short* __restrict__ B,         // [Mp,128] bf16
    float* __restrict__ csum,               // [Mp]
    int N)
{
  const int lane = threadIdx.x & 63;
  const int node = __builtin_amdgcn_readfirstlane(
      (int)blockIdx.x * 4 + ((int)threadIdx.x >> 6));
  if (node >= N) return;
  const int lo = row_start[node];
  const int hi = row_start[node + 1];

  const unsigned short* Xl = X + lane * 2;
  float2 acc = make_float2(0.f, 0.f);
  float cacc = 0.f;

  int e = lo;
  for (; e + 8 <= hi; e += 8) {
    int s[8]; float cv[8]; ushort2 x[8];
#pragma unroll
    for (int j = 0; j < 8; ++j) s[j] = __builtin_nontemporal_load(snd + e + j);
#pragma unroll
    for (int j = 0; j < 8; ++j) cv[j] = __builtin_nontemporal_load(conv + e + j);
#pragma unroll
    for (int j = 0; j < 8; ++j)
      x[j] = *reinterpret_cast<const ushort2*>(Xl + (size_t)s[j] * 128);
#pragma unroll
    for (int j = 0; j < 8; ++j) {
      acc.x = fmaf(cv[j], bf2f(x[j].x), acc.x);
      acc.y = fmaf(cv[j], bf2f(x[j].y), acc.y);
      cacc += cv[j];
    }
  }
  for (; e < hi; ++e) {
    const int s = snd[e];
    const float cv = conv[e];
    const ushort2 x = *reinterpret_cast<const ushort2*>(Xl + (size_t)s * 128);
    acc.x = fmaf(cv, bf2f(x.x), acc.x);
    acc.y = fmaf(cv, bf2f(x.y), acc.y);
    cacc += cv;
  }

  u16x2 r;
  r[0] = f2bf(acc.x); r[1] = f2bf(acc.y);
  __builtin_nontemporal_store(
      r, reinterpret_cast<u16x2*>(B + (size_t)node * 128 + lane * 2));
  if (lane == 0) __builtin_nontemporal_store(cacc, csum + node);
}

// ---------------------------------------------------------------------------
// MFMA dual-GEMM + bias + Hadamard, A/B-resident (R10/R11).
// Grid: Mp/256 blocks of 512 threads. A/B fragments loaded once into VGPRs;
// loop over 4 col-blocks staging the W slice in LDS. nt out stores.
// ---------------------------------------------------------------------------
__global__ __launch_bounds__(512) void gemm_combine_mfma(
    const unsigned short* __restrict__ A,    // [Mp,256] bf16
    const unsigned short* __restrict__ B,    // [Mp,128] bf16
    const float* __restrict__ c1,            // [Mp]
    const float* __restrict__ c2,            // [Mp]
    const unsigned short* __restrict__ WmT,  // [256,256] bf16 (N-major)
    const float* __restrict__ bm,            // [256]
    const unsigned short* __restrict__ WsT,  // [256,128] bf16 (N-major)
    const float* __restrict__ bs,            // [256]
    float* __restrict__ out,                 // [M,256]
    int M)
{
  __shared__ unsigned short lWm[64][264];
  __shared__ unsigned short lWs[64][136];

  const int tid  = (int)threadIdx.x;
  const int lane = tid & 63;
  const int wv   = tid >> 6;
  const int l15  = lane & 15;
  const int lg   = lane >> 4;
  const int m0   = blockIdx.x * 256;

  const int rowA = m0 + wv * 32 + l15;

  bf16x8 afrag[2][8];
  bf16x8 bfrag[2][4];
#pragma unroll
  for (int k8 = 0; k8 < 8; ++k8) {
    const int ko = k8 * 32 + lg * 8;
    afrag[0][k8] = *reinterpret_cast<const bf16x8*>(A + (size_t)rowA * 256 + ko);
    afrag[1][k8] = *reinterpret_cast<const bf16x8*>(A + (size_t)(rowA + 16) * 256 + ko);
  }
#pragma unroll
  for (int k8 = 0; k8 < 4; ++k8) {
    const int ko = k8 * 32 + lg * 8;
    bfrag[0][k8] = *reinterpret_cast<const bf16x8*>(B + (size_t)rowA * 128 + ko);
    bfrag[1][k8] = *reinterpret_cast<const bf16x8*>(B + (size_t)(rowA + 16) * 128 + ko);
  }

  float k1v[2][4], k2v[2][4];
#pragma unroll
  for (int ms = 0; ms < 2; ++ms)
#pragma unroll
    for (int r = 0; r < 4; ++r) {
      const int row = m0 + wv * 32 + ms * 16 + lg * 4 + r;
      const bool v = row < M;
      k1v[ms][r] = v ? c1[row] : 0.f;
      k2v[ms][r] = v ? c2[row] : 0.f;
    }

  for (int cb = 0; cb < 4; ++cb) {
    const int colBlk = cb * 64;
    __syncthreads();
#pragma unroll
    for (int i = 0; i < 4; ++i) {
      const int idx = tid + i * 512;
      const int c = idx >> 5, k8b = (idx & 31) << 3;
      *reinterpret_cast<bf16x8*>(&lWm[c][k8b]) =
          *reinterpret_cast<const bf16x8*>(WmT + (size_t)(colBlk + c) * 256 + k8b);
    }
#pragma unroll
    for (int i = 0; i < 2; ++i) {
      const int idx = tid + i * 512;
      const int c = idx >> 4, k8b = (idx & 15) << 3;
      *reinterpret_cast<bf16x8*>(&lWs[c][k8b]) =
          *reinterpret_cast<const bf16x8*>(WsT + (size_t)(colBlk + c) * 128 + k8b);
    }
    __syncthreads();

    f32x4 accM[2][4];
    f32x4 accS[2][4];
#pragma unroll
    for (int ms = 0; ms < 2; ++ms)
#pragma unroll
      for (int n = 0; n < 4; ++n) {
        accM[ms][n] = (f32x4)0.f;
        accS[ms][n] = (f32x4)0.f;
      }

#pragma unroll
    for (int k8 = 0; k8 < 8; ++k8) {
      const int ko = k8 * 32 + lg * 8;
#pragma unroll
      for (int n = 0; n < 4; ++n) {
        const bf16x8 w = *reinterpret_cast<const bf16x8*>(&lWm[l15 + n * 16][ko]);
        accM[0][n] = __builtin_amdgcn_mfma_f32_16x16x32_bf16(afrag[0][k8], w, accM[0][n], 0, 0, 0);
        accM[1][n] = __builtin_amdgcn_mfma_f32_16x16x32_bf16(afrag[1][k8], w, accM[1][n], 0, 0, 0);
      }
    }
#pragma unroll
    for (int k8 = 0; k8 < 4; ++k8) {
      const int ko = k8 * 32 + lg * 8;
#pragma unroll
      for (int n = 0; n < 4; ++n) {
        const bf16x8 w = *reinterpret_cast<const bf16x8*>(&lWs[l15 + n * 16][ko]);
        accS[0][n] = __builtin_amdgcn_mfma_f32_16x16x32_bf16(bfrag[0][k8], w, accS[0][n], 0, 0, 0);
        accS[1][n] = __builtin_amdgcn_mfma_f32_16x16x32_bf16(bfrag[1][k8], w, accS[1][n], 0, 0, 0);
      }
    }

    float bmv[4], bsv[4];
#pragma unroll
    for (int n = 0; n < 4; ++n) {
      bmv[n] = bm[colBlk + n * 16 + l15];
      bsv[n] = bs[colBlk + n * 16 + l15];
    }
#pragma unroll
    for (int ms = 0; ms < 2; ++ms) {
      const int rbase = m0 + wv * 32 + ms * 16 + lg * 4;
#pragma unroll
      for (int r = 0; r < 4; ++r) {
        const int row = rbase + r;
        if (row < M) {
#pragma unroll
          for (int n = 0; n < 4; ++n) {
            const int col = colBlk + n * 16 + l15;
            const float mv = accM[ms][n][r] + k1v[ms][r] * bmv[n];
            const float sv = accS[ms][n][r] + k2v[ms][r] * bsv[n];
            __builtin_nontemporal_store(mv * sv, out + (size_t)row * 256 + col);
          }
        }
      }
    }
  }
}

extern "C" void kernel_launch(void* const* d_in, const int* in_sizes, int n_in,
                              void* d_out, int out_size, void* d_ws, size_t ws_size,
                              hipStream_t stream) {
  const float* node_features  = (const float*)d_in[0];   // [50000,256]
  const float* hedge_features = (const float*)d_in[1];   // [25000,128]
  const int*   node_senders   = (const int*)d_in[2];     // [E]
  const int*   node_receivers = (const int*)d_in[3];     // [E] sorted
  const float* node_conv      = (const float*)d_in[4];   // [E]
  const int*   h2n_senders    = (const int*)d_in[5];     // [E2]
  const int*   h2n_receivers  = (const int*)d_in[6];     // [E2] sorted
  const float* h2n_conv       = (const float*)d_in[7];   // [E2]
  const float* Wm             = (const float*)d_in[8];   // [256,256]
  const float* bm             = (const float*)d_in[9];   // [256]
  const float* Ws             = (const float*)d_in[10];  // [128,256]
  const float* bs             = (const float*)d_in[11];  // [256]
  float* out = (float*)d_out;

  const int M   = in_sizes[0] / 256;       // 50000 nodes
  const int Nh  = in_sizes[1] / 128;       // 25000 hedges
  const int E   = in_sizes[2];             // 800000
  const int E2  = in_sizes[5];             // 400000
  const int Mp  = ((M + 255) / 256) * 256; // padded rows for 256-row GEMM tiles

  // Workspace layout (bf16 = unsigned short):
  //   A[Mp,256] | B[Mp,128] | Xb[M,256] | Hb[Nh,128] | WmT[256,256]
  //   | WsT[256,128] | c1 f32[Mp] | c2 f32[Mp] | ro1 [M+1] | ro2 [M+1]
  unsigned short* Ab  = (unsigned short*)d_ws;
  unsigned short* Bb  = Ab + (size_t)Mp * 256;
  unsigned short* Xb  = Bb + (size_t)Mp * 128;
  unsigned short* Hb  = Xb + (size_t)M * 256;
  unsigned short* WmT = Hb + (size_t)Nh * 128;
  unsigned short* WsT = WmT + 256 * 256;
  float* c1 = (float*)(WsT + 256 * 128);
  float* c2 = c1 + Mp;
  int*   ro1 = (int*)(c2 + Mp);
  int*   ro2 = ro1 + (M + 1);

  const int nX4 = M * 256 / 4, nH4 = Nh * 128 / 4;
  const int bX  = (nX4 + 255) / 256;
  const int bH  = (nH4 + 255) / 256;
  const int bE1 = (E + 255) / 256;
  const int bE2 = (E2 + 255) / 256;

  // 1) prep for the node pipeline only (gates scatter_node).
  prep_node<<<bX + bE1, 256, 0, stream>>>(
      node_features, node_receivers, E, M, Xb, ro1, nX4);

  // 2) long-pole scatter.
  scatter_node_seg<<<(M + 3) / 4, 256, 0, stream>>>(
      Xb, node_senders, node_conv, ro1, Ab, c1, M);

  // 3) hedge/weight prep fills scatter_node's drain tail.
  prep_rest<<<bH + bE2 + 96, 256, 0, stream>>>(
      hedge_features, h2n_receivers, E2, M, Wm, Ws, Hb, ro2, WmT, WsT, nH4);

  scatter_hedge_seg<<<(M + 3) / 4, 256, 0, stream>>>(
      Hb, h2n_senders, h2n_conv, ro2, Bb, c2, M);

  gemm_combine_mfma<<<Mp / 256, 512, 0, stream>>>(
      Ab, Bb, c1, c2, WmT, bm, WsT, bs, out, M);
}

// Round 13
// 122.672 us; speedup vs baseline: 1.0124x; 1.0124x over previous
//
#include <hip/hip_runtime.h>

// ---------------------------------------------------------------------------
// Pipeline (algebraically restructured from the reference):
//   Xb = bf16(node_features), Hb = bf16(hedge_features)     (prep_all)
//   A[n,:]  = sum_{e: rcv=n} conv_e * Xb[snd_e,:]           (f32 acc -> bf16)
//   c1[n]   = sum_{e: rcv=n} conv_e
//   B[n,:]  = sum_{e2} conv2_e * Hb[snd_e,:]                (f32 acc -> bf16)
//   c2[n]   = sum conv2_e
//   out     = (A@Wm + c1*bm) .* (B@Ws + c2*bs)   -- bf16 MFMA, f32 accum
//
// R13 = R11 (best measured, 122.3 us) + hedge scatter at 8 B/lane:
// lane = (edge-slot, channel-quad), one gather instruction = 2 edges x full
// 256 B row, 16 edges per unrolled batch (~1 batch/node at mean degree 8).
// R12's prep split reverted (neutral). scatter_node untouched (fabric floor:
// 3.75 TB/s TCC rate, byte-proportional, 6 mechanisms tried).
// ---------------------------------------------------------------------------

typedef __attribute__((ext_vector_type(8))) short bf16x8;
typedef __attribute__((ext_vector_type(4))) float f32x4;
typedef __attribute__((ext_vector_type(4))) unsigned short u16x4;

static __device__ __forceinline__ unsigned short f2bf(float f) {
  unsigned u = __float_as_uint(f);
  u += 0x7fff + ((u >> 16) & 1);          // round-to-nearest-even
  return (unsigned short)(u >> 16);
}
static __device__ __forceinline__ float bf2f(unsigned short h) {
  return __uint_as_float((unsigned)h << 16);
}

// ---------------------------------------------------------------------------
// prep_all: blockIdx ranges ->
//   [0,bX)     : cvt X f32 -> Xb bf16
//   [bX,+bH)   : cvt H f32 -> Hb bf16
//   [..,+bE1)  : row offsets for node_receivers
//   [..,+bE2)  : row offsets for h2n_receivers
//   [..,+64)   : transpose Wm (256x256) -> WmT bf16
//   [..,+32)   : transpose Ws (128x256) -> WsT bf16
// ---------------------------------------------------------------------------
__global__ __launch_bounds__(256) void prep_all(
    const float* __restrict__ X, const float* __restrict__ H,
    const int* __restrict__ rcv1, int E1,
    const int* __restrict__ rcv2, int E2, int N,
    const float* __restrict__ Wm, const float* __restrict__ Ws,
    unsigned short* __restrict__ Xb, unsigned short* __restrict__ Hb,
    int* __restrict__ ro1, int* __restrict__ ro2,
    unsigned short* __restrict__ WmT, unsigned short* __restrict__ WsT,
    int nX4, int nH4)
{
  __shared__ float t[32][33];
  const int tid = (int)threadIdx.x;
  int b = (int)blockIdx.x;

  const int bX  = (nX4 + 255) / 256;
  const int bH  = (nH4 + 255) / 256;
  const int bE1 = (E1 + 255) / 256;
  const int bE2 = (E2 + 255) / 256;

  if (b < bX) {                       // ---- cvt X ----
    const int i = b * 256 + tid;
    if (i < nX4) {
      const float4 v = reinterpret_cast<const float4*>(X)[i];
      reinterpret_cast<ushort4*>(Xb)[i] =
          make_ushort4(f2bf(v.x), f2bf(v.y), f2bf(v.z), f2bf(v.w));
    }
    return;
  }
  b -= bX;
  if (b < bH) {                       // ---- cvt H ----
    const int i = b * 256 + tid;
    if (i < nH4) {
      const float4 v = reinterpret_cast<const float4*>(H)[i];
      reinterpret_cast<ushort4*>(Hb)[i] =
          make_ushort4(f2bf(v.x), f2bf(v.y), f2bf(v.z), f2bf(v.w));
    }
    return;
  }
  b -= bH;
  if (b < bE1) {                      // ---- row offsets 1 ----
    const int e = b * 256 + tid;
    if (e < E1) {
      const int c = rcv1[e];
      const int p = (e == 0) ? -1 : rcv1[e - 1];
      for (int n = p + 1; n <= c; ++n) ro1[n] = e;
      if (e == E1 - 1)
        for (int n = c + 1; n <= N; ++n) ro1[n] = E1;
    }
    return;
  }
  b -= bE1;
  if (b < bE2) {                      // ---- row offsets 2 ----
    const int e = b * 256 + tid;
    if (e < E2) {
      const int c = rcv2[e];
      const int p = (e == 0) ? -1 : rcv2[e - 1];
      for (int n = p + 1; n <= c; ++n) ro2[n] = e;
      if (e == E2 - 1)
        for (int n = c + 1; n <= N; ++n) ro2[n] = E2;
    }
    return;
  }
  b -= bE2;
  {
    // ---- weight transposes: Wm tiles [0,64), Ws tiles [64,96) ----
    const float* W; unsigned short* WT; int K, Nn, tile;
    if (b < 64) { W = Wm; WT = WmT; K = 256; Nn = 256; tile = b; }
    else        { W = Ws; WT = WsT; K = 128; Nn = 256; tile = b - 64; }
    const int ntiles_n = Nn / 32;
    const int n0 = (tile % ntiles_n) * 32;
    const int k0 = (tile / ntiles_n) * 32;
    const int tx = tid & 31, ty = tid >> 5;   // 32 x 8
#pragma unroll
    for (int i = 0; i < 32; i += 8)
      t[ty + i][tx] = W[(size_t)(k0 + ty + i) * Nn + n0 + tx];
    __syncthreads();
#pragma unroll
    for (int i = 0; i < 32; i += 8)
      WT[(size_t)(n0 + ty + i) * K + k0 + tx] = f2bf(t[tx][ty + i]);
  }
}

// One wave per node, C=256 bf16 channels (ushort4 per lane). No atomics.
// 16/4/1 unmasked batches (fastest measured); nt idx loads, nt A/c store.
__global__ __launch_bounds__(256) void scatter_node_seg(
    const unsigned short* __restrict__ X,   // [Nsrc,256] bf16
    const int* __restrict__ snd,
    const float* __restrict__ conv,
    const int* __restrict__ row_start,      // [N+1]
    unsigned short* __restrict__ A,         // [Mp,256] bf16
    float* __restrict__ csum,               // [Mp]
    int N)
{
  const int lane = threadIdx.x & 63;
  const int node = __builtin_amdgcn_readfirstlane(
      (int)blockIdx.x * 4 + ((int)threadIdx.x >> 6));
  if (node >= N) return;
  const int lo = row_start[node];
  const int hi = row_start[node + 1];

  const unsigned short* Xl = X + lane * 4;
  float4 acc = make_float4(0.f, 0.f, 0.f, 0.f);
  float cacc = 0.f;

  int e = lo;
  for (; e + 16 <= hi; e += 16) {
    int s[16]; float cv[16]; ushort4 x[16];
#pragma unroll
    for (int j = 0; j < 16; ++j) s[j] = __builtin_nontemporal_load(snd + e + j);
#pragma unroll
    for (int j = 0; j < 16; ++j) cv[j] = __builtin_nontemporal_load(conv + e + j);
#pragma unroll
    for (int j = 0; j < 16; ++j)
      x[j] = *reinterpret_cast<const ushort4*>(Xl + (size_t)s[j] * 256);
#pragma unroll
    for (int j = 0; j < 16; ++j) {
      acc.x = fmaf(cv[j], bf2f(x[j].x), acc.x);
      acc.y = fmaf(cv[j], bf2f(x[j].y), acc.y);
      acc.z = fmaf(cv[j], bf2f(x[j].z), acc.z);
      acc.w = fmaf(cv[j], bf2f(x[j].w), acc.w);
      cacc += cv[j];
    }
  }
  for (; e + 4 <= hi; e += 4) {
    int s[4]; float cv[4]; ushort4 x[4];
#pragma unroll
    for (int j = 0; j < 4; ++j) s[j] = __builtin_nontemporal_load(snd + e + j);
#pragma unroll
    for (int j = 0; j < 4; ++j) cv[j] = __builtin_nontemporal_load(conv + e + j);
#pragma unroll
    for (int j = 0; j < 4; ++j)
      x[j] = *reinterpret_cast<const ushort4*>(Xl + (size_t)s[j] * 256);
#pragma unroll
    for (int j = 0; j < 4; ++j) {
      acc.x = fmaf(cv[j], bf2f(x[j].x), acc.x);
      acc.y = fmaf(cv[j], bf2f(x[j].y), acc.y);
      acc.z = fmaf(cv[j], bf2f(x[j].z), acc.z);
      acc.w = fmaf(cv[j], bf2f(x[j].w), acc.w);
      cacc += cv[j];
    }
  }
  for (; e < hi; ++e) {
    const int s = snd[e];
    const float cv = conv[e];
    const ushort4 x = *reinterpret_cast<const ushort4*>(Xl + (size_t)s * 256);
    acc.x = fmaf(cv, bf2f(x.x), acc.x);
    acc.y = fmaf(cv, bf2f(x.y), acc.y);
    acc.z = fmaf(cv, bf2f(x.z), acc.z);
    acc.w = fmaf(cv, bf2f(x.w), acc.w);
    cacc += cv;
  }

  u16x4 r;
  r[0] = f2bf(acc.x); r[1] = f2bf(acc.y);
  r[2] = f2bf(acc.z); r[3] = f2bf(acc.w);
  __builtin_nontemporal_store(
      r, reinterpret_cast<u16x4*>(A + (size_t)node * 256 + lane * 4));
  if (lane == 0) __builtin_nontemporal_store(cacc, csum + node);
}

// One wave per node, C=128 bf16 channels. 8 B/lane: lane = (es = lane>>5,
// cp = lane&31); one gather instruction covers 2 edges x full 256 B row.
// 16 edges per unrolled batch; masked tail batch; shfl_xor(32) combine.
__global__ __launch_bounds__(256) void scatter_hedge_seg(
    const unsigned short* __restrict__ X,   // [Nsrc,128] bf16
    const int* __restrict__ snd,
    const float* __restrict__ conv,
    const int* __restrict__ row_start,      // [N+1]
    unsigned short* __restrict__ B,         // [Mp,128] bf16
    float* __restrict__ csum,               // [Mp]
    int N)
{
  const int lane = threadIdx.x & 63;
  const int node = __builtin_amdgcn_readfirstlane(
      (int)blockIdx.x * 4 + ((int)threadIdx.x >> 6));
  if (node >= N) return;
  const int lo = row_start[node];
  const int hi = row_start[node + 1];

  const int es = lane >> 5;            // edge slot 0..1
  const int cp = lane & 31;            // channel quad (4 ch)
  const unsigned short* Xl = X + cp * 4;

  float4 acc = make_float4(0.f, 0.f, 0.f, 0.f);
  float cacc = 0.f;

  const int nfull = (hi - lo) & ~15;
  int e0 = lo;
  for (; e0 < lo + nfull; e0 += 16) {        // unmasked: 16 edges (8 per slot)
    int s[8]; float cv[8]; ushort4 x[8];
#pragma unroll
    for (int j = 0; j < 8; ++j) {
      const int e = e0 + j * 2 + es;
      s[j]  = __builtin_nontemporal_load(snd + e);
      cv[j] = __builtin_nontemporal_load(conv + e);
    }
#pragma unroll
    for (int j = 0; j < 8; ++j)
      x[j] = *reinterpret_cast<const ushort4*>(Xl + (size_t)s[j] * 128);
#pragma unroll
    for (int j = 0; j < 8; ++j) {
      acc.x = fmaf(cv[j], bf2f(x[j].x), acc.x);
      acc.y = fmaf(cv[j], bf2f(x[j].y), acc.y);
      acc.z = fmaf(cv[j], bf2f(x[j].z), acc.z);
      acc.w = fmaf(cv[j], bf2f(x[j].w), acc.w);
      cacc += cv[j];
    }
  }
  if (e0 < hi) {                             // single masked tail batch
    int s[8]; float cv[8]; ushort4 x[8];
#pragma unroll
    for (int j = 0; j < 8; ++j) {
      const int e = e0 + j * 2 + es;
      const bool v = e < hi;
      const int ec = v ? e : (hi - 1);
      s[j]  = snd[ec];
      cv[j] = v ? conv[ec] : 0.f;
    }
#pragma unroll
    for (int j = 0; j < 8; ++j)
      x[j] = *reinterpret_cast<const ushort4*>(Xl + (size_t)s[j] * 128);
#pragma unroll
    for (int j = 0; j < 8; ++j) {
      acc.x = fmaf(cv[j], bf2f(x[j].x), acc.x);
      acc.y = fmaf(cv[j], bf2f(x[j].y), acc.y);
      acc.z = fmaf(cv[j], bf2f(x[j].z), acc.z);
      acc.w = fmaf(cv[j], bf2f(x[j].w), acc.w);
      cacc += cv[j];
    }
  }

  // combine the two edge slots (lanes l <-> l^32)
  acc.x += __shfl_xor(acc.x, 32);
  acc.y += __shfl_xor(acc.y, 32);
  acc.z += __shfl_xor(acc.z, 32);
  acc.w += __shfl_xor(acc.w, 32);
  cacc  += __shfl_xor(cacc, 32);

  if (es == 0) {
    u16x4 r;
    r[0] = f2bf(acc.x); r[1] = f2bf(acc.y);
    r[2] = f2bf(acc.z); r[3] = f2bf(acc.w);
    __builtin_nontemporal_store(
        r, reinterpret_cast<u16x4*>(B + (size_t)node * 128 + cp * 4));
    if (lane == 0) __builtin_nontemporal_store(cacc, csum + node);
  }
}

// ---------------------------------------------------------------------------
// MFMA dual-GEMM + bias + Hadamard, A/B-resident (R10/R11).
// Grid: Mp/256 blocks of 512 threads. A/B fragments loaded once into VGPRs;
// loop over 4 col-blocks staging the W slice in LDS. nt out stores.
// mfma_f32_16x16x32_bf16 fragments:
//   A-frag: row = lane&15, k = 8*(lane>>4) + j
//   B-frag: col = lane&15, k = 8*(lane>>4) + j
//   C/D   : col = lane&15, row = 4*(lane>>4) + reg   [m89-verified]
// ---------------------------------------------------------------------------
__global__ __launch_bounds__(512) void gemm_combine_mfma(
    const unsigned short* __restrict__ A,    // [Mp,256] bf16
    const unsigned short* __restrict__ B,    // [Mp,128] bf16
    const float* __restrict__ c1,            // [Mp]
    const float* __restrict__ c2,            // [Mp]
    const unsigned short* __restrict__ WmT,  // [256,256] bf16 (N-major)
    const float* __restrict__ bm,            // [256]
    const unsigned short* __restrict__ WsT,  // [256,128] bf16 (N-major)
    const float* __restrict__ bs,            // [256]
    float* __restrict__ out,                 // [M,256]
    int M)
{
  __shared__ unsigned short lWm[64][264];
  __shared__ unsigned short lWs[64][136];

  const int tid  = (int)threadIdx.x;
  const int lane = tid & 63;
  const int wv   = tid >> 6;
  const int l15  = lane & 15;
  const int lg   = lane >> 4;
  const int m0   = blockIdx.x * 256;

  const int rowA = m0 + wv * 32 + l15;

  bf16x8 afrag[2][8];
  bf16x8 bfrag[2][4];
#pragma unroll
  for (int k8 = 0; k8 < 8; ++k8) {
    const int ko = k8 * 32 + lg * 8;
    afrag[0][k8] = *reinterpret_cast<const bf16x8*>(A + (size_t)rowA * 256 + ko);
    afrag[1][k8] = *reinterpret_cast<const bf16x8*>(A + (size_t)(rowA + 16) * 256 + ko);
  }
#pragma unroll
  for (int k8 = 0; k8 < 4; ++k8) {
    const int ko = k8 * 32 + lg * 8;
    bfrag[0][k8] = *reinterpret_cast<const bf16x8*>(B + (size_t)rowA * 128 + ko);
    bfrag[1][k8] = *reinterpret_cast<const bf16x8*>(B + (size_t)(rowA + 16) * 128 + ko);
  }

  float k1v[2][4], k2v[2][4];
#pragma unroll
  for (int ms = 0; ms < 2; ++ms)
#pragma unroll
    for (int r = 0; r < 4; ++r) {
      const int row = m0 + wv * 32 + ms * 16 + lg * 4 + r;
      const bool v = row < M;
      k1v[ms][r] = v ? c1[row] : 0.f;
      k2v[ms][r] = v ? c2[row] : 0.f;
    }

  for (int cb = 0; cb < 4; ++cb) {
    const int colBlk = cb * 64;
    __syncthreads();
#pragma unroll
    for (int i = 0; i < 4; ++i) {
      const int idx = tid + i * 512;
      const int c = idx >> 5, k8b = (idx & 31) << 3;
      *reinterpret_cast<bf16x8*>(&lWm[c][k8b]) =
          *reinterpret_cast<const bf16x8*>(WmT + (size_t)(colBlk + c) * 256 + k8b);
    }
#pragma unroll
    for (int i = 0; i < 2; ++i) {
      const int idx = tid + i * 512;
      const int c = idx >> 4, k8b = (idx & 15) << 3;
      *reinterpret_cast<bf16x8*>(&lWs[c][k8b]) =
          *reinterpret_cast<const bf16x8*>(WsT + (size_t)(colBlk + c) * 128 + k8b);
    }
    __syncthreads();

    f32x4 accM[2][4];
    f32x4 accS[2][4];
#pragma unroll
    for (int ms = 0; ms < 2; ++ms)
#pragma unroll
      for (int n = 0; n < 4; ++n) {
        accM[ms][n] = (f32x4)0.f;
        accS[ms][n] = (f32x4)0.f;
      }

#pragma unroll
    for (int k8 = 0; k8 < 8; ++k8) {
      const int ko = k8 * 32 + lg * 8;
#pragma unroll
      for (int n = 0; n < 4; ++n) {
        const bf16x8 w = *reinterpret_cast<const bf16x8*>(&lWm[l15 + n * 16][ko]);
        accM[0][n] = __builtin_amdgcn_mfma_f32_16x16x32_bf16(afrag[0][k8], w, accM[0][n], 0, 0, 0);
        accM[1][n] = __builtin_amdgcn_mfma_f32_16x16x32_bf16(afrag[1][k8], w, accM[1][n], 0, 0, 0);
      }
    }
#pragma unroll
    for (int k8 = 0; k8 < 4; ++k8) {
      const int ko = k8 * 32 + lg * 8;
#pragma unroll
      for (int n = 0; n < 4; ++n) {
        const bf16x8 w = *reinterpret_cast<const bf16x8*>(&lWs[l15 + n * 16][ko]);
        accS[0][n] = __builtin_amdgcn_mfma_f32_16x16x32_bf16(bfrag[0][k8], w, accS[0][n], 0, 0, 0);
        accS[1][n] = __builtin_amdgcn_mfma_f32_16x16x32_bf16(bfrag[1][k8], w, accS[1][n], 0, 0, 0);
      }
    }

    float bmv[4], bsv[4];
#pragma unroll
    for (int n = 0; n < 4; ++n) {
      bmv[n] = bm[colBlk + n * 16 + l15];
      bsv[n] = bs[colBlk + n * 16 + l15];
    }
#pragma unroll
    for (int ms = 0; ms < 2; ++ms) {
      const int rbase = m0 + wv * 32 + ms * 16 + lg * 4;
#pragma unroll
      for (int r = 0; r < 4; ++r) {
        const int row = rbase + r;
        if (row < M) {
#pragma unroll
          for (int n = 0; n < 4; ++n) {
            const int col = colBlk + n * 16 + l15;
            const float mv = accM[ms][n][r] + k1v[ms][r] * bmv[n];
            const float sv = accS[ms][n][r] + k2v[ms][r] * bsv[n];
            __builtin_nontemporal_store(mv * sv, out + (size_t)row * 256 + col);
          }
        }
      }
    }
  }
}

extern "C" void kernel_launch(void* const* d_in, const int* in_sizes, int n_in,
                              void* d_out, int out_size, void* d_ws, size_t ws_size,
                              hipStream_t stream) {
  const float* node_features  = (const float*)d_in[0];   // [50000,256]
  const float* hedge_features = (const float*)d_in[1];   // [25000,128]
  const int*   node_senders   = (const int*)d_in[2];     // [E]
  const int*   node_receivers = (const int*)d_in[3];     // [E] sorted
  const float* node_conv      = (const float*)d_in[4];   // [E]
  const int*   h2n_senders    = (const int*)d_in[5];     // [E2]
  const int*   h2n_receivers  = (const int*)d_in[6];     // [E2] sorted
  const float* h2n_conv       = (const float*)d_in[7];   // [E2]
  const float* Wm             = (const float*)d_in[8];   // [256,256]
  const float* bm             = (const float*)d_in[9];   // [256]
  const float* Ws             = (const float*)d_in[10];  // [128,256]
  const float* bs             = (const float*)d_in[11];  // [256]
  float* out = (float*)d_out;

  const int M   = in_sizes[0] / 256;       // 50000 nodes
  const int Nh  = in_sizes[1] / 128;       // 25000 hedges
  const int E   = in_sizes[2];             // 800000
  const int E2  = in_sizes[5];             // 400000
  const int Mp  = ((M + 255) / 256) * 256; // padded rows for 256-row GEMM tiles

  // Workspace layout (bf16 = unsigned short):
  //   A[Mp,256] | B[Mp,128] | Xb[M,256] | Hb[Nh,128] | WmT[256,256]
  //   | WsT[256,128] | c1 f32[Mp] | c2 f32[Mp] | ro1 [M+1] | ro2 [M+1]
  unsigned short* Ab  = (unsigned short*)d_ws;
  unsigned short* Bb  = Ab + (size_t)Mp * 256;
  unsigned short* Xb  = Bb + (size_t)Mp * 128;
  unsigned short* Hb  = Xb + (size_t)M * 256;
  unsigned short* WmT = Hb + (size_t)Nh * 128;
  unsigned short* WsT = WmT + 256 * 256;
  float* c1 = (float*)(WsT + 256 * 128);
  float* c2 = c1 + Mp;
  int*   ro1 = (int*)(c2 + Mp);
  int*   ro2 = ro1 + (M + 1);

  const int nX4 = M * 256 / 4, nH4 = Nh * 128 / 4;
  const int bX  = (nX4 + 255) / 256;
  const int bH  = (nH4 + 255) / 256;
  const int bE1 = (E + 255) / 256;
  const int bE2 = (E2 + 255) / 256;
  const int prep_blocks = bX + bH + bE1 + bE2 + 64 + 32;

  prep_all<<<prep_blocks, 256, 0, stream>>>(
      node_features, hedge_features,
      node_receivers, E, h2n_receivers, E2, M,
      Wm, Ws, Xb, Hb, ro1, ro2, WmT, WsT, nX4, nH4);

  // One wave per node: 4 waves per block.
  scatter_node_seg<<<(M + 3) / 4, 256, 0, stream>>>(
      Xb, node_senders, node_conv, ro1, Ab, c1, M);
  scatter_hedge_seg<<<(M + 3) / 4, 256, 0, stream>>>(
      Hb, h2n_senders, h2n_conv, ro2, Bb, c2, M);

  gemm_combine_mfma<<<Mp / 256, 512, 0, stream>>>(
      Ab, Bb, c1, c2, WmT, bm, WsT, bs, out, M);
}